// Round 5
// baseline (237.784 us; speedup 1.0000x reference)
//
#include <hip/hip_runtime.h>
#include <hip/hip_bf16.h>

#define TOKENS 4096
#define HDIM 1024
#define NEXP 16
#define BN 64            // output cols per block
#define NT (HDIM / BN)   // 16 col-blocks
#define MGRP 5           // 16-row token groups per wave per pass
#define GP (8 * MGRP)    // 40 groups per pass per block

typedef __bf16 bf16x8 __attribute__((ext_vector_type(8)));
typedef __bf16 bf16x4 __attribute__((ext_vector_type(4)));
typedef float f32x4 __attribute__((ext_vector_type(4)));

// ---------------- Gate: fp32-exact logits, softmax, top-2 + fused bf16 token cvt ----------------
__global__ __launch_bounds__(256) void gate_kernel(
    const float* __restrict__ tokens, const float* __restrict__ gate_w,
    int* __restrict__ tok_idx, float* __restrict__ tok_w, __bf16* __restrict__ tok_bf) {
  int lane = threadIdx.x & 63;
  int wv = threadIdx.x >> 6;
  int token = blockIdx.x * 4 + wv;
  const float* trow = tokens + (size_t)token * HDIM;

  float4 tv[4];
#pragma unroll
  for (int s = 0; s < 4; ++s) tv[s] = *(const float4*)(trow + s * 256 + lane * 4);

  // fused fp32->bf16 token conversion (row already in registers)
#pragma unroll
  for (int s = 0; s < 4; ++s) {
    bf16x4 v;
    v[0] = (__bf16)tv[s].x; v[1] = (__bf16)tv[s].y;
    v[2] = (__bf16)tv[s].z; v[3] = (__bf16)tv[s].w;
    *(bf16x4*)(tok_bf + (size_t)token * HDIM + s * 256 + lane * 4) = v;
  }

  float lg[NEXP];
#pragma unroll
  for (int e = 0; e < NEXP; ++e) {
    float d = 0.f;
#pragma unroll
    for (int s = 0; s < 4; ++s) {
      float4 g = *(const float4*)(gate_w + e * HDIM + s * 256 + lane * 4);
      d += tv[s].x * g.x + tv[s].y * g.y + tv[s].z * g.z + tv[s].w * g.w;
    }
#pragma unroll
    for (int off = 32; off; off >>= 1) d += __shfl_xor(d, off);
    lg[e] = d;
  }

  int i0 = 0; float b0 = lg[0];
#pragma unroll
  for (int e = 1; e < NEXP; ++e) if (lg[e] > b0) { b0 = lg[e]; i0 = e; }
  int i1 = -1; float b1 = -1e30f;
#pragma unroll
  for (int e = 0; e < NEXP; ++e) {
    if (e == i0) continue;
    if (lg[e] > b1) { b1 = lg[e]; i1 = e; }
  }
  float s = 0.f;
#pragma unroll
  for (int e = 0; e < NEXP; ++e) s += expf(lg[e] - b0);
  float w0 = 1.0f / s;
  float w1 = expf(b1 - b0) / s;

  if (lane == 0) {
    tok_idx[token * 2 + 0] = i0;
    tok_idx[token * 2 + 1] = i1;
    tok_w[token * 2 + 0] = w0;
    tok_w[token * 2 + 1] = w1;
  }
}

// ---------------- Per-expert list compaction (LDS cursor) ----------------
__global__ __launch_bounds__(1024) void build_lists_kernel(
    const int* __restrict__ tok_idx, const float* __restrict__ tok_w,
    int* __restrict__ counts, int* __restrict__ list_tok, float* __restrict__ list_w) {
  int e = blockIdx.x;
  __shared__ int cur;
  if (threadIdx.x == 0) cur = 0;
  __syncthreads();
  for (int s = threadIdx.x; s < TOKENS * 2; s += 1024) {
    if (tok_idx[s] == e) {
      int pos = atomicAdd(&cur, 1);
      list_tok[e * TOKENS + pos] = s >> 1;
      list_w[e * TOKENS + pos] = tok_w[s];
    }
  }
  __syncthreads();
  if (threadIdx.x == 0) counts[e] = cur;
}

// ---------------- Weight-stationary grouped GEMM ----------------
// Block (e, nt): stage B = W[e][nt*64 .. +64)[0..1024) fp32->bf16 into 128 KB LDS
// (XOR-swizzled 16B chunks: kc' = kc ^ (d&7)), one barrier, then waves free-run:
// each wave owns MGRP 16-row token groups, A-frags global->VGPR (L3-resident bf16),
// K-loop has NO barriers. Ragged tails: rows clamped, gate weight forced to 0.
__global__ __launch_bounds__(512, 2) void moe_gemm_kernel(
    const __bf16* __restrict__ tok_bf, const float* __restrict__ expert_w,
    const float* __restrict__ expert_b, const int* __restrict__ counts,
    const int* __restrict__ list_tok, const float* __restrict__ list_w,
    float* __restrict__ out) {
  int e = blockIdx.x;
  int nt = blockIdx.y;
  int cnt = counts[e];
  if (cnt == 0) return;
  const int lbase = e * TOKENS;

  __shared__ __bf16 Bl[BN * HDIM];   // 128 KB

  int tid = threadIdx.x;
  int lane = tid & 63;
  int wv = tid >> 6;

  // ---- stage B panel: 8192 16B-chunks, 16 per thread ----
  {
    const float* wbase = expert_w + ((size_t)e * HDIM + (size_t)nt * BN) * HDIM;
#pragma unroll
    for (int i = 0; i < 16; ++i) {
      int c = i * 512 + tid;
      int d = c >> 7, kc = c & 127;
      const float* src = wbase + (size_t)d * HDIM + kc * 8;
      float4 f0 = *(const float4*)(src);
      float4 f1 = *(const float4*)(src + 4);
      bf16x8 v;
      v[0] = (__bf16)f0.x; v[1] = (__bf16)f0.y; v[2] = (__bf16)f0.z; v[3] = (__bf16)f0.w;
      v[4] = (__bf16)f1.x; v[5] = (__bf16)f1.y; v[6] = (__bf16)f1.z; v[7] = (__bf16)f1.w;
      *(bf16x8*)(&Bl[d * HDIM + ((kc ^ (d & 7)) * 8)]) = v;
    }
  }
  __syncthreads();   // the ONLY barrier

  int lr = lane & 15;
  int lk = lane >> 4;

  int drow[4], dxor[4];
#pragma unroll
  for (int n = 0; n < 4; ++n) { int d = n * 16 + lr; drow[n] = d * HDIM; dxor[n] = d & 7; }

  int ngroups = (cnt + 15) >> 4;
  int npass = (ngroups + GP - 1) / GP;

  for (int p = 0; p < npass; ++p) {
    if (p * GP + wv >= ngroups) break;   // wave-uniform, no barriers downstream

    // token id for lane's row in each of this wave's MGRP groups
    int tok[MGRP];
#pragma unroll
    for (int i = 0; i < MGRP; ++i) {
      int g = p * GP + i * 8 + wv;
      int row = g * 16 + lr;
      tok[i] = list_tok[lbase + min(row, cnt - 1)];
    }

    f32x4 acc[MGRP][4] = {};

#pragma unroll 4
    for (int kb = 0; kb < HDIM / 32; ++kb) {
      bf16x8 a[MGRP], b[4];
#pragma unroll
      for (int i = 0; i < MGRP; ++i)
        a[i] = *(const bf16x8*)(tok_bf + (size_t)tok[i] * HDIM + kb * 32 + lk * 8);
#pragma unroll
      for (int n = 0; n < 4; ++n) {
        int kc = kb * 4 + lk;
        b[n] = *(const bf16x8*)(&Bl[drow[n] + ((kc ^ dxor[n]) * 8)]);
      }
#pragma unroll
      for (int i = 0; i < MGRP; ++i)
#pragma unroll
        for (int n = 0; n < 4; ++n)
          acc[i][n] = __builtin_amdgcn_mfma_f32_16x16x32_bf16(a[i], b[n], acc[i][n], 0, 0, 0);
    }

    // epilogue: C/D layout col = lane&15, row = (lane>>4)*4 + j
    const float* brow = expert_b + e * HDIM + nt * BN;
#pragma unroll
    for (int i = 0; i < MGRP; ++i) {
      int g = p * GP + i * 8 + wv;
#pragma unroll
      for (int j = 0; j < 4; ++j) {
        int row = g * 16 + lk * 4 + j;
        int cr = min(row, cnt - 1);
        int tokr = list_tok[lbase + cr];
        float gw = (row < cnt) ? list_w[lbase + row] : 0.f;   // padded rows add 0
        float* orow = out + (size_t)tokr * HDIM + nt * BN;
#pragma unroll
        for (int n = 0; n < 4; ++n) {
          int dc = n * 16 + lr;
          float v = acc[i][n][j] + brow[dc];
          v = fmaxf(v, 0.f) * gw;
          atomicAdd(orow + dc, v);
        }
      }
    }
  }
}

extern "C" void kernel_launch(void* const* d_in, const int* in_sizes, int n_in,
                              void* d_out, int out_size, void* d_ws, size_t ws_size,
                              hipStream_t stream) {
  const float* tokens = (const float*)d_in[0];
  const float* gate_w = (const float*)d_in[1];
  const float* expert_w = (const float*)d_in[2];
  const float* expert_b = (const float*)d_in[3];
  float* out = (float*)d_out;

  int* counts = (int*)d_ws;                           // 16
  int* tok_idx = counts + 16;                         // TOKENS*2
  float* tok_w = (float*)(tok_idx + TOKENS * 2);      // TOKENS*2
  int* list_tok = (int*)(tok_w + TOKENS * 2);         // NEXP*TOKENS
  float* list_w = (float*)(list_tok + NEXP * TOKENS); // NEXP*TOKENS
  size_t head = (size_t)(list_w + NEXP * TOKENS) - (size_t)d_ws;
  head = (head + 255) & ~(size_t)255;
  __bf16* tok_bf = (__bf16*)((char*)d_ws + head);     // 8 MB

  hipMemsetAsync(d_out, 0, (size_t)out_size * sizeof(float), stream);

  gate_kernel<<<TOKENS / 4, 256, 0, stream>>>(tokens, gate_w, tok_idx, tok_w, tok_bf);
  build_lists_kernel<<<NEXP, 1024, 0, stream>>>(tok_idx, tok_w, counts, list_tok, list_w);

  dim3 grid(NEXP, NT);
  moe_gemm_kernel<<<grid, 512, 0, stream>>>(tok_bf, expert_w, expert_b, counts,
                                            list_tok, list_w, out);
}